// Round 8
// baseline (35.596 us; speedup 1.0000x reference)
//
#include <hip/hip_runtime.h>

// UnitaryQuantizer: masked elementwise phase quantization.
// out[b][r][c] = (r + c <= N-2) ? quant(x[b][r][c]) : 0
// N = 512, B = 128, f32 in/out. Memory-bound (201 MB compulsory traffic:
// 67 MB live input read + 134 MB output write).
//
// R7 base (33.64 us, 4-deep MLP) -> 8-deep: 4096 blocks x 256 thr x 8 float4
// = n4 exactly. All 8 predicated loads issued before any compute.
// No cache hints (R3: nt-store worse, R5: nt-load much worse — live-input
// L3 retention is real).

#define N_DIM 512
#define UNROLL 8

typedef float floatx4 __attribute__((ext_vector_type(4)));

__device__ __forceinline__ floatx4 quant4(floatx4 v, int rc) {
    constexpr double PI_D   = 3.14159265358979323846;
    constexpr float TWO_PI  = (float)(2.0 * PI_D);
    constexpr float INV_2PI = (float)(1.0 / (2.0 * PI_D));
    constexpr float THR     = (float)(1.5 * PI_D);
    constexpr float PMIN    = (float)((0.015625 - 0.5) * PI_D);
    constexpr float PMAX    = (float)((1.5 - 0.0078125) * PI_D);
    constexpr float RATIO   = (float)((((1.5 - 0.0078125) * PI_D) -
                                       ((0.015625 - 0.5) * PI_D)) / 255.0);
    floatx4 o;
    #pragma unroll
    for (int j = 0; j < 4; ++j) {
        float m = v[j];
        m = m - TWO_PI * floorf(m * INV_2PI);   // mod 2pi (exact for [0,2pi))
        if (m > THR) m -= TWO_PI;               // wrap (1.5pi,2pi) -> negative
        m = fminf(fmaxf(m, PMIN), PMAX);        // clip
        float q = rintf((m - PMIN) / RATIO) * RATIO + PMIN;
        o[j] = ((rc + j) <= (N_DIM - 2)) ? q : 0.0f;
    }
    return o;
}

// Exact-shape kernel: gridDim.x*blockDim.x*UNROLL == n4, no bounds checks.
__global__ __launch_bounds__(256) void UnitaryQuantizer_kernel(
    const float* __restrict__ x, float* __restrict__ out)
{
    const floatx4* __restrict__ x4 = reinterpret_cast<const floatx4*>(x);
    floatx4* __restrict__ o4 = reinterpret_cast<floatx4*>(out);

    const int span = gridDim.x * blockDim.x;          // 1,048,576
    const int t    = blockIdx.x * blockDim.x + threadIdx.x;

    int   idx[UNROLL];
    int   rc[UNROLL];
    bool  live[UNROLL];
    #pragma unroll
    for (int k = 0; k < UNROLL; ++k) {
        idx[k] = t + k * span;
        const int e = idx[k] << 2;
        const int r = (e >> 9) & (N_DIM - 1);
        const int c = e & (N_DIM - 1);
        rc[k]   = r + c;
        live[k] = (rc[k] <= N_DIM - 2);
    }

    // Issue all UNROLL (predicated) loads before any compute: deep MLP.
    floatx4 v[UNROLL];
    #pragma unroll
    for (int k = 0; k < UNROLL; ++k) {
        v[k] = floatx4{0.f, 0.f, 0.f, 0.f};
        if (live[k]) v[k] = x4[idx[k]];
    }

    #pragma unroll
    for (int k = 0; k < UNROLL; ++k) {
        floatx4 o = {0.f, 0.f, 0.f, 0.f};
        if (live[k]) o = quant4(v[k], rc[k]);
        o4[idx[k]] = o;
    }
}

// Generic fallback (never taken for the 128x512x512 shape).
__global__ __launch_bounds__(256) void UnitaryQuantizer_generic(
    const float* __restrict__ x, float* __restrict__ out, int n4)
{
    const floatx4* __restrict__ x4 = reinterpret_cast<const floatx4*>(x);
    floatx4* __restrict__ o4 = reinterpret_cast<floatx4*>(out);
    const int stride = gridDim.x * blockDim.x;
    for (int t = blockIdx.x * blockDim.x + threadIdx.x; t < n4; t += stride) {
        const int e = t << 2;
        const int r = (e >> 9) & (N_DIM - 1);
        const int c = e & (N_DIM - 1);
        floatx4 o = {0.f, 0.f, 0.f, 0.f};
        if (r + c <= N_DIM - 2) o = quant4(x4[t], r + c);
        o4[t] = o;
    }
}

extern "C" void kernel_launch(void* const* d_in, const int* in_sizes, int n_in,
                              void* d_out, int out_size, void* d_ws, size_t ws_size,
                              hipStream_t stream) {
    const float* x = (const float*)d_in[0];
    float* out = (float*)d_out;
    const int n  = in_sizes[0];     // 128*512*512 = 33,554,432
    const int n4 = n >> 2;          // 8,388,608 float4

    const int block = 256;
    const int grid  = 4096;         // 4096*256*8 = 8,388,608 = n4 exactly

    if (n4 == grid * block * UNROLL) {
        UnitaryQuantizer_kernel<<<grid, block, 0, stream>>>(x, out);
    } else {
        UnitaryQuantizer_generic<<<2048, block, 0, stream>>>(x, out, n4);
    }
}

// Round 9
// 33.181 us; speedup vs baseline: 1.0728x; 1.0728x over previous
//
#include <hip/hip_runtime.h>

// UnitaryQuantizer: masked elementwise phase quantization.
// out[b][r][c] = (r + c <= N-2) ? quant(x[b][r][c]) : 0
// N = 512, B = 128, f32 in/out. Memory-bound (201 MB compulsory traffic:
// 67 MB live input read + 134 MB output write).
//
// FINAL (R7 config, 33.64 us = 5.97 TB/s effective, ~95% of copy ceiling):
// 8192 blocks x 256 thr x 4 float4 = n4 exactly; 4 independent predicated
// loads issued before any compute (4-deep MLP), no bounds checks.
// Swept and rejected: nt-store (R3, +2us), nt-load (R5, +5.5us — live-input
// L3 retention is real), 2-deep (R6, +1.1us), 8-deep (R8, +2us).

#define N_DIM 512

typedef float floatx4 __attribute__((ext_vector_type(4)));

__device__ __forceinline__ floatx4 quant4(floatx4 v, int rc) {
    constexpr double PI_D   = 3.14159265358979323846;
    constexpr float TWO_PI  = (float)(2.0 * PI_D);
    constexpr float INV_2PI = (float)(1.0 / (2.0 * PI_D));
    constexpr float THR     = (float)(1.5 * PI_D);
    constexpr float PMIN    = (float)((0.015625 - 0.5) * PI_D);
    constexpr float PMAX    = (float)((1.5 - 0.0078125) * PI_D);
    constexpr float RATIO   = (float)((((1.5 - 0.0078125) * PI_D) -
                                       ((0.015625 - 0.5) * PI_D)) / 255.0);
    floatx4 o;
    #pragma unroll
    for (int j = 0; j < 4; ++j) {
        float m = v[j];
        m = m - TWO_PI * floorf(m * INV_2PI);   // mod 2pi (exact for [0,2pi))
        if (m > THR) m -= TWO_PI;               // wrap (1.5pi,2pi) -> negative
        m = fminf(fmaxf(m, PMIN), PMAX);        // clip
        float q = rintf((m - PMIN) / RATIO) * RATIO + PMIN;
        o[j] = ((rc + j) <= (N_DIM - 2)) ? q : 0.0f;
    }
    return o;
}

// Exact-shape kernel: gridDim.x*blockDim.x*4 == n4, no bounds checks.
__global__ __launch_bounds__(256) void UnitaryQuantizer_kernel(
    const float* __restrict__ x, float* __restrict__ out)
{
    const floatx4* __restrict__ x4 = reinterpret_cast<const floatx4*>(x);
    floatx4* __restrict__ o4 = reinterpret_cast<floatx4*>(out);

    const int span = gridDim.x * blockDim.x;          // 2,097,152
    const int t    = blockIdx.x * blockDim.x + threadIdx.x;

    int   idx[4];
    int   rc[4];
    bool  live[4];
    #pragma unroll
    for (int k = 0; k < 4; ++k) {
        idx[k] = t + k * span;
        const int e = idx[k] << 2;
        const int r = (e >> 9) & (N_DIM - 1);
        const int c = e & (N_DIM - 1);
        rc[k]   = r + c;
        live[k] = (rc[k] <= N_DIM - 2);
    }

    // Issue all 4 (predicated) loads before any compute: 4-deep MLP.
    floatx4 v[4];
    #pragma unroll
    for (int k = 0; k < 4; ++k) {
        v[k] = floatx4{0.f, 0.f, 0.f, 0.f};
        if (live[k]) v[k] = x4[idx[k]];
    }

    #pragma unroll
    for (int k = 0; k < 4; ++k) {
        floatx4 o = {0.f, 0.f, 0.f, 0.f};
        if (live[k]) o = quant4(v[k], rc[k]);
        o4[idx[k]] = o;
    }
}

// Generic fallback (never taken for the 128x512x512 shape).
__global__ __launch_bounds__(256) void UnitaryQuantizer_generic(
    const float* __restrict__ x, float* __restrict__ out, int n4)
{
    const floatx4* __restrict__ x4 = reinterpret_cast<const floatx4*>(x);
    floatx4* __restrict__ o4 = reinterpret_cast<floatx4*>(out);
    const int stride = gridDim.x * blockDim.x;
    for (int t = blockIdx.x * blockDim.x + threadIdx.x; t < n4; t += stride) {
        const int e = t << 2;
        const int r = (e >> 9) & (N_DIM - 1);
        const int c = e & (N_DIM - 1);
        floatx4 o = {0.f, 0.f, 0.f, 0.f};
        if (r + c <= N_DIM - 2) o = quant4(x4[t], r + c);
        o4[t] = o;
    }
}

extern "C" void kernel_launch(void* const* d_in, const int* in_sizes, int n_in,
                              void* d_out, int out_size, void* d_ws, size_t ws_size,
                              hipStream_t stream) {
    const float* x = (const float*)d_in[0];
    float* out = (float*)d_out;
    const int n  = in_sizes[0];     // 128*512*512 = 33,554,432
    const int n4 = n >> 2;          // 8,388,608 float4

    const int block = 256;
    const int grid  = 8192;         // 8192*256*4 = 8,388,608 = n4 exactly

    if (n4 == grid * block * 4) {
        UnitaryQuantizer_kernel<<<grid, block, 0, stream>>>(x, out);
    } else {
        UnitaryQuantizer_generic<<<2048, block, 0, stream>>>(x, out, n4);
    }
}